// Round 15
// baseline (505.391 us; speedup 1.0000x reference)
//
#include <hip/hip_runtime.h>

#define BSZ 16
#define NNODE 1024
#define NT (BSZ*NNODE)      // 16384 total nodes
#define EG 131072            // graph edges (before self loops)
#define ET (EG+NT)           // 147456 edges incl self loops

typedef unsigned short bfu;  // raw bf16
typedef __attribute__((ext_vector_type(8))) short short8v;   // 8 bf16 (4 VGPRs)
typedef __attribute__((ext_vector_type(4))) float f32x4;     // MFMA accum

typedef __attribute__((address_space(1))) const unsigned gU32;
typedef __attribute__((address_space(3))) unsigned lU32;
#define GLL16(gp, lp) __builtin_amdgcn_global_load_lds((gU32*)(gp), (lU32*)(lp), 16, 0, 0)

__device__ __forceinline__ float b2f(unsigned u) { return __uint_as_float(u << 16); }
__device__ __forceinline__ bfu f2b(float f) {
  unsigned u = __float_as_uint(f);
  u += 0x7fffu + ((u >> 16) & 1u);
  return (bfu)(u >> 16);
}
__device__ __forceinline__ void unpack8(uint4 u, float* f) {
  f[0] = b2f(u.x & 0xffffu); f[1] = b2f(u.x >> 16);
  f[2] = b2f(u.y & 0xffffu); f[3] = b2f(u.y >> 16);
  f[4] = b2f(u.z & 0xffffu); f[5] = b2f(u.z >> 16);
  f[6] = b2f(u.w & 0xffffu); f[7] = b2f(u.w >> 16);
}
__device__ __forceinline__ void edge_sd(const int* __restrict__ ei, int e, int& s, int& d) {
  if (e < EG) { s = ei[e]; d = ei[EG + e]; } else { s = e - EG; d = e - EG; }
}
// chunk swizzle (involution): spreads the 4 k8-chunks of each row across bank groups
__device__ __forceinline__ int swz(int c) {
  int r = c >> 2;
  return (c & ~3) | ((c & 3) ^ ((r & 3) ^ ((r >> 2) & 3)));
}

// ============ MFMA GEMM: C[M,N] = A[M,K](bf16) x Bt[N,K](bf16)^T ============
// 128x128 tile, BK=32, 4 waves (2x2 of 64x64), 16x16x32 bf16.
// DOUBLE-BUFFERED global_load_lds staging: issue next-tile loads BEFORE compute,
// single barrier per K-step (guide T3 minimum-2-phase recipe).
// EPI 0: bf16 out = acc; GAT-alpha partials STORED to av_s/av_d[r][hd][blk][wc]
// EPI 1: bf16 out = elu(acc + b1[c] + b2[c] + agg[r*aggld+c])
// EPI 2: bf16 out = acc + b1[c] + b2[c] + 0.5*(agg[..c]+agg[..128+c])   (layer3 head-mean)
// EPI 3: f32 out  = acc + resid[r*ldo+c]                                 (pre-LN)
// EPI 7: bf16 out = exp(acc) (z-batched); row-sum partials STORED [z][r][blk][wc] (16)
// EPI 8: batched qkv projections: z<2 -> [bh][node][64] at z*2M; z==2 -> vt [bh][d][node] at 4M
template<int EPI>
__global__ __launch_bounds__(256)
void mgemm(const bfu* __restrict__ A, int lda, long long sA,
           const bfu* __restrict__ Bt, int ldb, long long sB,
           int K,
           bfu* __restrict__ outb, float* __restrict__ outf, int ldo, long long sO,
           const float* __restrict__ b1, const float* __restrict__ b2,
           const bfu* __restrict__ agg, int aggld,
           const float* __restrict__ resid,
           const float* __restrict__ asrc, const float* __restrict__ adst,
           float* __restrict__ av_s, float* __restrict__ av_d)
{
  __shared__ bfu As[2][128 * 32];
  __shared__ bfu Bs[2][128 * 32];
  const int tid = threadIdx.x;
  const int z = blockIdx.z;
  const int n0 = blockIdx.x * 128, r0 = blockIdx.y * 128;
  const bfu* Az = A + (size_t)z * sA;
  const bfu* Bz = Bt + (size_t)z * sB;

  const int w = tid >> 6, l = tid & 63;
  const int wr = w >> 1, wc = w & 1;
  const int lr = l & 15;
  const int k8 = l >> 4;

  f32x4 acc[4][4] = {};

  const int s0c = swz(tid), s1c = swz(tid + 256);
  const bfu* ga0 = Az + (size_t)(r0 + (s0c >> 2)) * lda + (s0c & 3) * 8;
  const bfu* ga1 = Az + (size_t)(r0 + (s1c >> 2)) * lda + (s1c & 3) * 8;
  const bfu* gb0 = Bz + (size_t)(n0 + (s0c >> 2)) * ldb + (s0c & 3) * 8;
  const bfu* gb1 = Bz + (size_t)(n0 + (s1c >> 2)) * ldb + (s1c & 3) * 8;

  // prologue: stage k=0 into buf 0
  GLL16(ga0, As[0] + tid * 8);
  GLL16(ga1, As[0] + (tid + 256) * 8);
  GLL16(gb0, Bs[0] + tid * 8);
  GLL16(gb1, Bs[0] + (tid + 256) * 8);
  ga0 += 32; ga1 += 32; gb0 += 32; gb1 += 32;

  int cur = 0;
  for (int k0 = 0; k0 < K; k0 += 32) {
    __syncthreads();   // buf[cur] loads complete; prior reads of buf[cur^1] done
    if (k0 + 32 < K) { // issue NEXT tile into buf[cur^1] -> overlaps compute below
      GLL16(ga0, As[cur ^ 1] + tid * 8);
      GLL16(ga1, As[cur ^ 1] + (tid + 256) * 8);
      GLL16(gb0, Bs[cur ^ 1] + tid * 8);
      GLL16(gb1, Bs[cur ^ 1] + (tid + 256) * 8);
      ga0 += 32; ga1 += 32; gb0 += 32; gb1 += 32;
    }
    short8v af[4], bfr[4];
    #pragma unroll
    for (int mi = 0; mi < 4; ++mi) {
      const int R = wr * 64 + mi * 16 + lr;
      af[mi] = *(const short8v*)(As[cur] + swz(R * 4 + k8) * 8);
    }
    #pragma unroll
    for (int ni = 0; ni < 4; ++ni) {
      const int R = wc * 64 + ni * 16 + lr;
      bfr[ni] = *(const short8v*)(Bs[cur] + swz(R * 4 + k8) * 8);
    }
    #pragma unroll
    for (int mi = 0; mi < 4; ++mi)
      #pragma unroll
      for (int ni = 0; ni < 4; ++ni)
        acc[mi][ni] = __builtin_amdgcn_mfma_f32_16x16x32_bf16(af[mi], bfr[ni], acc[mi][ni], 0, 0, 0);
    cur ^= 1;
  }

  const int rr = k8 * 4;
  float ps[4][4], pd[4][4];
  if (EPI == 0 || EPI == 7) {
    #pragma unroll
    for (int mi = 0; mi < 4; ++mi)
      #pragma unroll
      for (int i = 0; i < 4; ++i) { ps[mi][i] = 0.f; pd[mi][i] = 0.f; }
  }

  #pragma unroll
  for (int mi = 0; mi < 4; ++mi) {
    #pragma unroll
    for (int ni = 0; ni < 4; ++ni) {
      #pragma unroll
      for (int i = 0; i < 4; ++i) {
        const int r = r0 + wr * 64 + mi * 16 + rr + i;
        const int cc = n0 + wc * 64 + ni * 16 + lr;
        float val = acc[mi][ni][i];
        if (EPI == 0) {
          outb[(size_t)r * ldo + cc] = f2b(val);
          ps[mi][i] = fmaf(val, asrc[cc], ps[mi][i]);
          pd[mi][i] = fmaf(val, adst[cc], pd[mi][i]);
        } else if (EPI == 1) {
          val += b1[cc] + b2[cc] + b2f(agg[(size_t)r * aggld + cc]);
          val = val > 0.f ? val : expm1f(val);
          outb[(size_t)r * ldo + cc] = f2b(val);
        } else if (EPI == 2) {
          val += b1[cc] + b2[cc]
               + 0.5f * (b2f(agg[(size_t)r * aggld + cc]) + b2f(agg[(size_t)r * aggld + 128 + cc]));
          outb[(size_t)r * ldo + cc] = f2b(val);
        } else if (EPI == 3) {
          outf[(size_t)r * ldo + cc] = val + resid[(size_t)r * ldo + cc];
        } else if (EPI == 7) {
          float e = expf(val);
          outb[(size_t)z * sO + (size_t)r * ldo + cc] = f2b(e);
          ps[mi][i] += e;
        } else { // EPI == 8: batched q/k/v projections
          if (z < 2) {
            outb[(size_t)z * 2097152 + ((size_t)((r >> 10) * 2 + (cc >> 6))) * 65536
                 + (size_t)(r & 1023) * 64 + (cc & 63)] = f2b(val);
          } else {
            outb[4194304 + ((size_t)((r >> 10) * 2 + (cc >> 6))) * 65536
                 + (size_t)(cc & 63) * 1024 + (r & 1023)] = f2b(val);
          }
        }
      }
    }
  }

  if (EPI == 0) {
    const int half = ldo >> 1;
    const int hd = n0 / half;                 // head, uniform per block
    const int blk = (n0 & (half - 1)) >> 7;   // block index within head (0 or 1)
    #pragma unroll
    for (int mi = 0; mi < 4; ++mi) {
      #pragma unroll
      for (int i = 0; i < 4; ++i) {
        float s = ps[mi][i], d = pd[mi][i];
        #pragma unroll
        for (int m = 1; m < 16; m <<= 1) { s += __shfl_xor(s, m); d += __shfl_xor(d, m); }
        if (lr == 0) {
          const int r = r0 + wr * 64 + mi * 16 + rr + i;
          // unique slot per (block, wave-column): no race
          av_s[((size_t)r * 2 + hd) * 4 + blk * 2 + wc] = s;
          av_d[((size_t)r * 2 + hd) * 4 + blk * 2 + wc] = d;
        }
      }
    }
  } else if (EPI == 7) {
    #pragma unroll
    for (int mi = 0; mi < 4; ++mi) {
      #pragma unroll
      for (int i = 0; i < 4; ++i) {
        float s = ps[mi][i];
        #pragma unroll
        for (int m = 1; m < 16; m <<= 1) s += __shfl_xor(s, m);
        if (lr == 0) {
          const int r = r0 + wr * 64 + mi * 16 + rr + i;
          av_s[((size_t)z * 1024 + r) * 16 + ((n0 >> 7) << 1) + wc] = s;  // unique slot
        }
      }
    }
  }
}

// ============ PV: O = (expS(bf16) x vt^T) / rowsum, per bh ============
// double-buffered staging, single barrier per K-step.
__global__ __launch_bounds__(256)
void pv_k(const bfu* __restrict__ Pb, const bfu* __restrict__ vt,
          const float* __restrict__ rowsum16, bfu* __restrict__ catb)
{
  __shared__ bfu As[2][128 * 32];
  __shared__ bfu Bs[2][64 * 32];
  const int tid = threadIdx.x;
  const int bh = blockIdx.z;
  const int r0 = blockIdx.y * 128;
  const bfu* Az = Pb + (size_t)bh * 1048576;
  const bfu* Bz = vt + (size_t)bh * 65536;
  const int w = tid >> 6, l = tid & 63;
  const int lr = l & 15, k8 = l >> 4;

  f32x4 acc[2][4] = {};

  const int s0c = swz(tid), s1c = swz(tid + 256);
  const bfu* ga0 = Az + (size_t)(r0 + (s0c >> 2)) * 1024 + (s0c & 3) * 8;
  const bfu* ga1 = Az + (size_t)(r0 + (s1c >> 2)) * 1024 + (s1c & 3) * 8;
  const bfu* gb0 = Bz + (size_t)(s0c >> 2) * 1024 + (s0c & 3) * 8;

  GLL16(ga0, As[0] + tid * 8);
  GLL16(ga1, As[0] + (tid + 256) * 8);
  GLL16(gb0, Bs[0] + tid * 8);
  ga0 += 32; ga1 += 32; gb0 += 32;

  int cur = 0;
  for (int k0 = 0; k0 < 1024; k0 += 32) {
    __syncthreads();
    if (k0 + 32 < 1024) {
      GLL16(ga0, As[cur ^ 1] + tid * 8);
      GLL16(ga1, As[cur ^ 1] + (tid + 256) * 8);
      GLL16(gb0, Bs[cur ^ 1] + tid * 8);
      ga0 += 32; ga1 += 32; gb0 += 32;
    }
    short8v af[2], bfr[4];
    #pragma unroll
    for (int mi = 0; mi < 2; ++mi) {
      const int R = w * 32 + mi * 16 + lr;
      af[mi] = *(const short8v*)(As[cur] + swz(R * 4 + k8) * 8);
    }
    #pragma unroll
    for (int ni = 0; ni < 4; ++ni) {
      const int R = ni * 16 + lr;
      bfr[ni] = *(const short8v*)(Bs[cur] + swz(R * 4 + k8) * 8);
    }
    #pragma unroll
    for (int mi = 0; mi < 2; ++mi)
      #pragma unroll
      for (int ni = 0; ni < 4; ++ni)
        acc[mi][ni] = __builtin_amdgcn_mfma_f32_16x16x32_bf16(af[mi], bfr[ni], acc[mi][ni], 0, 0, 0);
    cur ^= 1;
  }

  const int b = bh >> 1, h = bh & 1;
  const int rr = k8 * 4;
  #pragma unroll
  for (int mi = 0; mi < 2; ++mi) {
    #pragma unroll
    for (int i = 0; i < 4; ++i) {
      const int qn = r0 + w * 32 + mi * 16 + rr + i;
      float sm = 0.f;
      #pragma unroll
      for (int j = 0; j < 16; ++j) sm += rowsum16[((size_t)bh * 1024 + qn) * 16 + j];
      const float inv = 1.f / sm;
      #pragma unroll
      for (int ni = 0; ni < 4; ++ni) {
        const int d = ni * 16 + lr;
        catb[((size_t)(b * 1024 + qn)) * 256 + 128 + h * 64 + d] = f2b(acc[mi][ni][i] * inv);
      }
    }
  }
}

// ============ normalize: f32 attn = bf16 expS / rowsum ============
__global__ __launch_bounds__(256)
void normk(const bfu* __restrict__ Pb, const float* __restrict__ rowsum16, float* __restrict__ Pf)
{
  const int w = threadIdx.x >> 6, l = threadIdx.x & 63;
  const size_t R = (size_t)blockIdx.x * 4 + w;
  const bfu* brow = Pb + R * 1024;
  float* frow = Pf + R * 1024;
  float sm = 0.f;
  #pragma unroll
  for (int j = 0; j < 16; ++j) sm += rowsum16[R * 16 + j];
  const float inv = 1.f / sm;
  uint4 u0 = *(const uint4*)(brow + l * 16);
  uint4 u1 = *(const uint4*)(brow + l * 16 + 8);
  float v[16];
  unpack8(u0, v); unpack8(u1, v + 8);
  #pragma unroll
  for (int j = 0; j < 4; ++j) {
    float4 o;
    o.x = v[j*4+0]*inv; o.y = v[j*4+1]*inv; o.z = v[j*4+2]*inv; o.w = v[j*4+3]*inv;
    *(float4*)(frow + l * 16 + j * 4) = o;
  }
}

// ============ merged conversions: z<3 -> q/k/v f32->bf16; z==3 -> all weights transposed ============
__global__ __launch_bounds__(256)
void conv_all(const float* __restrict__ q, const float* __restrict__ k, const float* __restrict__ v,
              bfu* __restrict__ qo, bfu* __restrict__ ko, bfu* __restrict__ vo,
              const float* __restrict__ Wq, const float* __restrict__ Wk, const float* __restrict__ Wv,
              const float* __restrict__ Wfc, const float* __restrict__ g1W, const float* __restrict__ l1W,
              const float* __restrict__ g2W, const float* __restrict__ l2W, const float* __restrict__ g3W,
              const float* __restrict__ l3W, bfu* __restrict__ out)
{
  const int zz = blockIdx.y;
  if (zz < 3) {
    const int i = blockIdx.x * 256 + threadIdx.x;
    if (i >= NT * 64) return;
    const float* src = zz == 0 ? q : (zz == 1 ? k : v);
    bfu* dst = zz == 0 ? qo : (zz == 1 ? ko : vo);
    float4 x = ((const float4*)src)[i];
    uint2 o;
    o.x = (unsigned)f2b(x.x) | ((unsigned)f2b(x.y) << 16);
    o.y = (unsigned)f2b(x.z) | ((unsigned)f2b(x.w) << 16);
    ((uint2*)dst)[i] = o;
    return;
  }
  const int idx = blockIdx.x * 256 + threadIdx.x;
  const float* src; int kb, N, base; float sc = 1.f;
  if (idx < 98304)        { int wi = idx >> 15; base = wi << 15; src = wi == 0 ? Wq : (wi == 1 ? Wk : Wv); kb = 8; N = 128; if (wi == 0) sc = 0.125f; }
  else if (idx < 163840)  { base = 98304;  src = Wfc; kb = 8; N = 256; }
  else if (idx < 294912)  { base = 163840; src = g1W; kb = 8; N = 512; }
  else if (idx < 425984)  { base = 294912; src = l1W; kb = 8; N = 512; }
  else if (idx < 688128)  { base = 425984; src = g2W; kb = 9; N = 512; }
  else if (idx < 950272)  { base = 688128; src = l2W; kb = 9; N = 512; }
  else if (idx < 1081344) { base = 950272; src = g3W; kb = 9; N = 256; }
  else if (idx < 1146880) { base = 1081344; src = l3W; kb = 9; N = 128; }
  else return;
  const int local = idx - base;
  const int n = local >> kb, kk = local & ((1 << kb) - 1);
  out[idx] = f2b(src[(size_t)kk * N + n] * sc);
}

__global__ void zero_i(int* p, int n) {
  int i = blockIdx.x * 256 + threadIdx.x;
  if (i < n) p[i] = 0;
}

// ---------------- CSR build ----------------
__global__ void csr_count(const int* __restrict__ ei, int* __restrict__ deg) {
  int e = blockIdx.x * 256 + threadIdx.x;
  if (e >= ET) return;
  int s, d; edge_sd(ei, e, s, d);
  atomicAdd(&deg[d], 1);
}
__global__ __launch_bounds__(1024)
void csr_scan(const int* __restrict__ deg, int* __restrict__ rowptr, int* __restrict__ fillc) {
  __shared__ int sums[1024];
  const int t = threadIdx.x;
  const int base = t * 16;
  int loc[16]; int s = 0;
  #pragma unroll
  for (int k = 0; k < 16; ++k) { loc[k] = deg[base + k]; s += loc[k]; }
  sums[t] = s;
  __syncthreads();
  for (int off = 1; off < 1024; off <<= 1) {
    int v = (t >= off) ? sums[t - off] : 0;
    __syncthreads();
    sums[t] += v;
    __syncthreads();
  }
  int run = sums[t] - s;
  #pragma unroll
  for (int k = 0; k < 16; ++k) { rowptr[base + k] = run; fillc[base + k] = run; run += loc[k]; }
  if (t == 1023) rowptr[NT] = sums[1023];
}
// stores SRC node directly (not edge id)
__global__ void csr_fill(const int* __restrict__ ei, int* __restrict__ fillc, int* __restrict__ srcs) {
  int e = blockIdx.x * 256 + threadIdx.x;
  if (e >= ET) return;
  int s, d; edge_sd(ei, e, s, d);
  int pos = atomicAdd(&fillc[d], 1);
  srcs[pos] = s;
}

// ---------------- fused GAT softmax + aggregation ----------------
// partial layout: [node][head(2)][blk(2)][wc(2)] = 8 f32 per node
template<int CT, int NBLK>  // CT: 512 (layers 1/2) or 256 (layer 3); NBLK: col-blocks/head
__global__ __launch_bounds__(256)
void aggf_k(const int* __restrict__ rowptr, const int* __restrict__ srcs,
            const float* __restrict__ avsp, const float* __restrict__ avdp,
            const bfu* __restrict__ h, bfu* __restrict__ agg)
{
  const int n = blockIdx.x, tid = threadIdx.x;
  float ad0 = avdp[(size_t)n * 8 + 0] + avdp[(size_t)n * 8 + 1];
  float ad1 = avdp[(size_t)n * 8 + 4] + avdp[(size_t)n * 8 + 5];
  if (NBLK > 1) {
    ad0 += avdp[(size_t)n * 8 + 2] + avdp[(size_t)n * 8 + 3];
    ad1 += avdp[(size_t)n * 8 + 6] + avdp[(size_t)n * 8 + 7];
  }
  float a0 = 0.f, a1 = 0.f, sum0 = 0.f, sum1 = 0.f;
  const int beg = rowptr[n], end = rowptr[n + 1];
  for (int idx = beg; idx < end; ++idx) {
    const int s = srcs[idx];
    float as0 = avsp[(size_t)s * 8 + 0] + avsp[(size_t)s * 8 + 1];
    float as1 = avsp[(size_t)s * 8 + 4] + avsp[(size_t)s * 8 + 5];
    if (NBLK > 1) {
      as0 += avsp[(size_t)s * 8 + 2] + avsp[(size_t)s * 8 + 3];
      as1 += avsp[(size_t)s * 8 + 6] + avsp[(size_t)s * 8 + 7];
    }
    float al0 = as0 + ad0; al0 = al0 > 0.f ? al0 : 0.2f * al0;
    float al1 = as1 + ad1; al1 = al1 > 0.f ? al1 : 0.2f * al1;
    const float e0 = expf(al0), e1 = expf(al1);
    sum0 += e0; sum1 += e1;
    if (CT == 512) {
      a0 = fmaf(e0, b2f(h[(size_t)s * 512 + tid]), a0);
      a1 = fmaf(e1, b2f(h[(size_t)s * 512 + 256 + tid]), a1);
    } else {
      const float ev = tid < 128 ? e0 : e1;
      a0 = fmaf(ev, b2f(h[(size_t)s * 256 + tid]), a0);
    }
  }
  if (CT == 512) {
    agg[(size_t)n * 512 + tid] = f2b(a0 / (sum0 + 1e-16f));
    agg[(size_t)n * 512 + 256 + tid] = f2b(a1 / (sum1 + 1e-16f));
  } else {
    const float sv = tid < 128 ? sum0 : sum1;
    agg[(size_t)n * 256 + tid] = f2b(a0 / (sv + 1e-16f));
  }
}

// ---------------- LayerNorm over 256, write f32 y ----------------
__global__ __launch_bounds__(256)
void ln_k(const float* __restrict__ x, const float* __restrict__ g, const float* __restrict__ bta,
          float* __restrict__ y)
{
  const int r = blockIdx.x, tid = threadIdx.x;
  float v = x[(size_t)r * 256 + tid];
  float s = v;
  #pragma unroll
  for (int off = 32; off; off >>= 1) s += __shfl_xor(s, off);
  __shared__ float red[4], red2[4];
  const int w = tid >> 6, lane = tid & 63;
  if (lane == 0) red[w] = s;
  __syncthreads();
  float mu = (red[0] + red[1] + red[2] + red[3]) * (1.f / 256.f);
  float dv = v - mu;
  float q2 = dv * dv;
  #pragma unroll
  for (int off = 32; off; off >>= 1) q2 += __shfl_xor(q2, off);
  if (lane == 0) red2[w] = q2;
  __syncthreads();
  float var = (red2[0] + red2[1] + red2[2] + red2[3]) * (1.f / 256.f);
  y[(size_t)r * 256 + tid] = dv * rsqrtf(var + 1e-6f) * g[tid] + bta[tid];
}

extern "C" void kernel_launch(void* const* d_in, const int* in_sizes, int n_in,
                              void* d_out, int out_size, void* d_ws, size_t ws_size,
                              hipStream_t stream)
{
  const float* q   = (const float*)d_in[0];
  const float* kin = (const float*)d_in[1];
  const float* vin = (const float*)d_in[2];
  const int*   ei  = (const int*)d_in[3];
  const float* Wq  = (const float*)d_in[4];
  const float* Wk  = (const float*)d_in[5];
  const float* Wv  = (const float*)d_in[6];
  const float* Wfc = (const float*)d_in[7];
  const float* g1W = (const float*)d_in[8],  *g1as = (const float*)d_in[9],  *g1ad = (const float*)d_in[10];
  const float* l1W = (const float*)d_in[12], *l1b = (const float*)d_in[13], *g1b = (const float*)d_in[11];
  const float* g2W = (const float*)d_in[14], *g2as = (const float*)d_in[15], *g2ad = (const float*)d_in[16], *g2b = (const float*)d_in[17];
  const float* l2W = (const float*)d_in[18], *l2b = (const float*)d_in[19];
  const float* g3W = (const float*)d_in[20], *g3as = (const float*)d_in[21], *g3ad = (const float*)d_in[22], *g3b = (const float*)d_in[23];
  const float* l3W = (const float*)d_in[24], *l3b = (const float*)d_in[25];
  const float* lng = (const float*)d_in[26], *lnb = (const float*)d_in[27];

  // ---- d_out regions (f32 output) ----
  float* ybuf = (float*)d_out;                          // y: NT*256 f32
  float* attn_out = ybuf + (size_t)NT * 256;            // attn: 32M f32 = 134.2 MB
  bfu* catb = (bfu*)d_out;                              // bf16 [NT][256] in y region

  // GAT scratch in attn region (dead before normk writes P over it)
  char* ap = (char*)attn_out;
  auto take_a = [&](size_t bytes) -> void* {
    void* r = (void*)ap; ap += (bytes + 255) & ~(size_t)255; return r;
  };
  bfu* q_bf = (bfu*)take_a((size_t)NT * 256 * 2);   // NOTE: q_bf/k_bf/v_bf contiguous (EPI 8 relies on stride NT*256)
  bfu* k_bf = (bfu*)take_a((size_t)NT * 256 * 2);
  bfu* v_bf = (bfu*)take_a((size_t)NT * 256 * 2);
  bfu* aggb  = (bfu*)take_a((size_t)NT * 512 * 2);
  float* avsp = (float*)take_a((size_t)NT * 8 * 4);  // alpha-src partials [r][hd][blk][wc]
  float* avdp = (float*)take_a((size_t)NT * 8 * 4);  // alpha-dst partials
  int* deg    = (int*)take_a((size_t)NT * 4);
  int* rowptr = (int*)take_a((size_t)(NT + 1) * 4);
  int* fillc  = (int*)take_a((size_t)NT * 4);
  int* srcs   = (int*)take_a((size_t)ET * 4);

  // ---- d_ws (~117 MB) ----
  char* p = (char*)d_ws;
  auto take = [&](size_t bytes) -> void* {
    void* r = (void*)p; p += (bytes + 255) & ~(size_t)255; return r;
  };
  bfu* hbuf = (bfu*)take((size_t)NT * 512 * 2);
  bfu* x1   = (bfu*)take((size_t)NT * 512 * 2);
  bfu* x2   = (bfu*)take((size_t)NT * 512 * 2);
  bfu* wall = (bfu*)take((size_t)1146880 * 2);               // all converted weights
  bfu* Pbuf = (bfu*)take((size_t)32 * 1048576 * 2);          // bf16 expS [32][1024][1024]
  float* rowsum16 = (float*)take((size_t)32 * 1024 * 16 * 4);// attn row-sum partials [bh][r][16]

  bfu* WqT  = wall;                 // WqT/WkT/WvT contiguous, stride 32768 (EPI 8)
  bfu* WfcT = wall + 98304;
  bfu* g1Wt = wall + 163840;
  bfu* l1Wt = wall + 294912;
  bfu* g2Wt = wall + 425984;
  bfu* l2Wt = wall + 688128;
  bfu* g3Wt = wall + 950272;
  bfu* l3Wt = wall + 1081344;

  // hbuf dead after layer-3 agg -> attention operand aliases
  bfu* qh2  = hbuf;                            // [32][1024][64] (EPI 8 z=0 base)
  bfu* khb2 = hbuf + (size_t)2 * 1024 * 1024;
  bfu* vt   = hbuf + (size_t)4 * 1024 * 1024;  // [32][64][1024]
  float* prelng = (float*)x1;                  // x1 dead after layer-2 gemms

  const int EB = (ET + 255) / 256;
  const long long zs = 0;
  #define NOAL nullptr, nullptr, nullptr, nullptr

  // conversions (fully merged: q/k/v bf16 + all weight transposes)
  conv_all<<<dim3(4480, 4), 256, 0, stream>>>(q, kin, vin, q_bf, k_bf, v_bf,
                                              Wq, Wk, Wv, Wfc, g1W, l1W, g2W, l2W, g3W, l3W, wall);

  // CSR build (srcs stored directly)
  zero_i<<<(NT + 255) / 256, 256, 0, stream>>>(deg, NT);
  csr_count<<<EB, 256, 0, stream>>>(ei, deg);
  csr_scan<<<1, 1024, 0, stream>>>(deg, rowptr, fillc);
  csr_fill<<<EB, 256, 0, stream>>>(ei, fillc, srcs);

  // ---- GAT layer 1 ----
  mgemm<0><<<dim3(4, 128), 256, 0, stream>>>(q_bf, 256, zs, g1Wt, 256, zs, 256, hbuf, nullptr, 512, zs, nullptr, nullptr, nullptr, 0, nullptr, g1as, g1ad, avsp, avdp);
  aggf_k<512, 2><<<NT, 256, 0, stream>>>(rowptr, srcs, avsp, avdp, hbuf, aggb);
  mgemm<1><<<dim3(4, 128), 256, 0, stream>>>(q_bf, 256, zs, l1Wt, 256, zs, 256, x1, nullptr, 512, zs, l1b, g1b, aggb, 512, nullptr, NOAL);

  // ---- GAT layer 2 ----
  mgemm<0><<<dim3(4, 128), 256, 0, stream>>>(x1, 512, zs, g2Wt, 512, zs, 512, hbuf, nullptr, 512, zs, nullptr, nullptr, nullptr, 0, nullptr, g2as, g2ad, avsp, avdp);
  aggf_k<512, 2><<<NT, 256, 0, stream>>>(rowptr, srcs, avsp, avdp, hbuf, aggb);
  mgemm<1><<<dim3(4, 128), 256, 0, stream>>>(x1, 512, zs, l2Wt, 512, zs, 512, x2, nullptr, 512, zs, l2b, g2b, aggb, 512, nullptr, NOAL);
  // x1 now dead.

  // ---- GAT layer 3 -> catb[:,0:128] ----
  mgemm<0><<<dim3(2, 128), 256, 0, stream>>>(x2, 512, zs, g3Wt, 512, zs, 512, hbuf, nullptr, 256, zs, nullptr, nullptr, nullptr, 0, nullptr, g3as, g3ad, avsp, avdp);
  aggf_k<256, 1><<<NT, 256, 0, stream>>>(rowptr, srcs, avsp, avdp, hbuf, aggb);
  mgemm<2><<<dim3(1, 128), 256, 0, stream>>>(x2, 512, zs, l3Wt, 512, zs, 512, catb, nullptr, 256, zs, l3b, g3b, aggb, 256, nullptr, NOAL);
  // hbuf now dead -> qh2/khb2/vt.

  // ---- q/k/v projections, batched over z (head-split layouts) ----
  mgemm<8><<<dim3(1, 128, 3), 256, 0, stream>>>(q_bf, 256, (long long)NT * 256, WqT, 256, 32768LL, 256, qh2, nullptr, 0, zs, nullptr, nullptr, nullptr, 0, nullptr, NOAL);

  // ---- attention: expS bf16 + rowsum partials -> normalize (f32 output) -> PV ----
  mgemm<7><<<dim3(8, 8, 32), 256, 0, stream>>>(qh2, 64, 65536LL, khb2, 64, 65536LL, 64, Pbuf, nullptr, 1024, 1048576LL, nullptr, nullptr, nullptr, 0, nullptr, nullptr, nullptr, rowsum16, nullptr);
  normk<<<8192, 256, 0, stream>>>(Pbuf, rowsum16, attn_out);
  pv_k<<<dim3(1, 8, 32), 256, 0, stream>>>(Pbuf, vt, rowsum16, catb);

  // ---- final FC + residual + LN ----
  mgemm<3><<<dim3(2, 128), 256, 0, stream>>>(catb, 256, zs, WfcT, 256, zs, 256, nullptr, prelng, 256, zs, nullptr, nullptr, nullptr, 0, q, NOAL);
  ln_k<<<NT, 256, 0, stream>>>(prelng, lng, lnb, ybuf);
}

// Round 16
// 478.599 us; speedup vs baseline: 1.0560x; 1.0560x over previous
//
#include <hip/hip_runtime.h>

#define BSZ 16
#define NNODE 1024
#define NT (BSZ*NNODE)      // 16384 total nodes
#define EG 131072            // graph edges (before self loops)
#define ET (EG+NT)           // 147456 edges incl self loops

typedef unsigned short bfu;  // raw bf16
typedef __attribute__((ext_vector_type(8))) short short8v;   // 8 bf16 (4 VGPRs)
typedef __attribute__((ext_vector_type(4))) float f32x4;     // MFMA accum

typedef __attribute__((address_space(1))) const unsigned gU32;
typedef __attribute__((address_space(3))) unsigned lU32;
#define GLL16(gp, lp) __builtin_amdgcn_global_load_lds((gU32*)(gp), (lU32*)(lp), 16, 0, 0)

__device__ __forceinline__ float b2f(unsigned u) { return __uint_as_float(u << 16); }
__device__ __forceinline__ bfu f2b(float f) {
  unsigned u = __float_as_uint(f);
  u += 0x7fffu + ((u >> 16) & 1u);
  return (bfu)(u >> 16);
}
__device__ __forceinline__ void unpack8(uint4 u, float* f) {
  f[0] = b2f(u.x & 0xffffu); f[1] = b2f(u.x >> 16);
  f[2] = b2f(u.y & 0xffffu); f[3] = b2f(u.y >> 16);
  f[4] = b2f(u.z & 0xffffu); f[5] = b2f(u.z >> 16);
  f[6] = b2f(u.w & 0xffffu); f[7] = b2f(u.w >> 16);
}
__device__ __forceinline__ void edge_sd(const int* __restrict__ ei, int e, int& s, int& d) {
  if (e < EG) { s = ei[e]; d = ei[EG + e]; } else { s = e - EG; d = e - EG; }
}
// chunk swizzle (involution): spreads the 4 k8-chunks of each row across bank groups
__device__ __forceinline__ int swz(int c) {
  int r = c >> 2;
  return (c & ~3) | ((c & 3) ^ ((r & 3) ^ ((r >> 2) & 3)));
}

// ============ MFMA GEMM: C[M,N] = A[M,K](bf16) x Bt[N,K](bf16)^T ============
// 128x128 tile, BK=32, 4 waves (2x2 of 64x64), 16x16x32 bf16, global_load_lds staging.
// (round-12 proven structure: single LDS buffer, GLL between the two barriers)
// EPI 0: bf16 out = acc; GAT-alpha partials STORED to av_s/av_d[r][hd][blk][wc]
// EPI 1: bf16 out = elu(acc + b1[c] + b2[c] + agg[r*aggld+c])
// EPI 2: bf16 out = acc + b1[c] + b2[c] + 0.5*(agg[..c]+agg[..128+c])   (layer3 head-mean)
// EPI 3: f32 out  = acc + resid[r*ldo+c]                                 (pre-LN)
// EPI 7: bf16 out = exp(acc) (z-batched); row-sum partials STORED [z][r][blk][wc] (16)
// EPI 8: batched qkv projections: z<2 -> [bh][node][64] at z*2M; z==2 -> vt [bh][d][node] at 4M
template<int EPI>
__global__ __launch_bounds__(256)
void mgemm(const bfu* __restrict__ A, int lda, long long sA,
           const bfu* __restrict__ Bt, int ldb, long long sB,
           int K,
           bfu* __restrict__ outb, float* __restrict__ outf, int ldo, long long sO,
           const float* __restrict__ b1, const float* __restrict__ b2,
           const bfu* __restrict__ agg, int aggld,
           const float* __restrict__ resid,
           const float* __restrict__ asrc, const float* __restrict__ adst,
           float* __restrict__ av_s, float* __restrict__ av_d)
{
  __shared__ bfu As[128 * 32];
  __shared__ bfu Bs[128 * 32];
  const int tid = threadIdx.x;
  const int z = blockIdx.z;
  const int n0 = blockIdx.x * 128, r0 = blockIdx.y * 128;
  const bfu* Az = A + (size_t)z * sA;
  const bfu* Bz = Bt + (size_t)z * sB;

  const int w = tid >> 6, l = tid & 63;
  const int wr = w >> 1, wc = w & 1;
  const int lr = l & 15;
  const int k8 = l >> 4;

  f32x4 acc[4][4] = {};

  const int s0c = swz(tid), s1c = swz(tid + 256);
  const bfu* ga0 = Az + (size_t)(r0 + (s0c >> 2)) * lda + (s0c & 3) * 8;
  const bfu* ga1 = Az + (size_t)(r0 + (s1c >> 2)) * lda + (s1c & 3) * 8;
  const bfu* gb0 = Bz + (size_t)(n0 + (s0c >> 2)) * ldb + (s0c & 3) * 8;
  const bfu* gb1 = Bz + (size_t)(n0 + (s1c >> 2)) * ldb + (s1c & 3) * 8;
  bfu* la0 = As + tid * 8;
  bfu* la1 = As + (tid + 256) * 8;
  bfu* lb0 = Bs + tid * 8;
  bfu* lb1 = Bs + (tid + 256) * 8;

  for (int k0 = 0; k0 < K; k0 += 32) {
    __syncthreads();
    GLL16(ga0, la0); GLL16(ga1, la1);
    GLL16(gb0, lb0); GLL16(gb1, lb1);
    ga0 += 32; ga1 += 32; gb0 += 32; gb1 += 32;
    __syncthreads();
    short8v af[4], bfr[4];
    #pragma unroll
    for (int mi = 0; mi < 4; ++mi) {
      const int R = wr * 64 + mi * 16 + lr;
      af[mi] = *(const short8v*)(As + swz(R * 4 + k8) * 8);
    }
    #pragma unroll
    for (int ni = 0; ni < 4; ++ni) {
      const int R = wc * 64 + ni * 16 + lr;
      bfr[ni] = *(const short8v*)(Bs + swz(R * 4 + k8) * 8);
    }
    #pragma unroll
    for (int mi = 0; mi < 4; ++mi)
      #pragma unroll
      for (int ni = 0; ni < 4; ++ni)
        acc[mi][ni] = __builtin_amdgcn_mfma_f32_16x16x32_bf16(af[mi], bfr[ni], acc[mi][ni], 0, 0, 0);
  }

  const int rr = k8 * 4;
  float ps[4][4], pd[4][4];
  if (EPI == 0 || EPI == 7) {
    #pragma unroll
    for (int mi = 0; mi < 4; ++mi)
      #pragma unroll
      for (int i = 0; i < 4; ++i) { ps[mi][i] = 0.f; pd[mi][i] = 0.f; }
  }

  #pragma unroll
  for (int mi = 0; mi < 4; ++mi) {
    #pragma unroll
    for (int ni = 0; ni < 4; ++ni) {
      #pragma unroll
      for (int i = 0; i < 4; ++i) {
        const int r = r0 + wr * 64 + mi * 16 + rr + i;
        const int cc = n0 + wc * 64 + ni * 16 + lr;
        float val = acc[mi][ni][i];
        if (EPI == 0) {
          outb[(size_t)r * ldo + cc] = f2b(val);
          ps[mi][i] = fmaf(val, asrc[cc], ps[mi][i]);
          pd[mi][i] = fmaf(val, adst[cc], pd[mi][i]);
        } else if (EPI == 1) {
          val += b1[cc] + b2[cc] + b2f(agg[(size_t)r * aggld + cc]);
          val = val > 0.f ? val : expm1f(val);
          outb[(size_t)r * ldo + cc] = f2b(val);
        } else if (EPI == 2) {
          val += b1[cc] + b2[cc]
               + 0.5f * (b2f(agg[(size_t)r * aggld + cc]) + b2f(agg[(size_t)r * aggld + 128 + cc]));
          outb[(size_t)r * ldo + cc] = f2b(val);
        } else if (EPI == 3) {
          outf[(size_t)r * ldo + cc] = val + resid[(size_t)r * ldo + cc];
        } else if (EPI == 7) {
          float e = expf(val);
          outb[(size_t)z * sO + (size_t)r * ldo + cc] = f2b(e);
          ps[mi][i] += e;
        } else { // EPI == 8: batched q/k/v projections
          if (z < 2) {
            outb[(size_t)z * 2097152 + ((size_t)((r >> 10) * 2 + (cc >> 6))) * 65536
                 + (size_t)(r & 1023) * 64 + (cc & 63)] = f2b(val);
          } else {
            outb[4194304 + ((size_t)((r >> 10) * 2 + (cc >> 6))) * 65536
                 + (size_t)(cc & 63) * 1024 + (r & 1023)] = f2b(val);
          }
        }
      }
    }
  }

  if (EPI == 0) {
    const int half = ldo >> 1;
    const int hd = n0 / half;                 // head, uniform per block
    const int blk = (n0 & (half - 1)) >> 7;   // block index within head (0 or 1)
    #pragma unroll
    for (int mi = 0; mi < 4; ++mi) {
      #pragma unroll
      for (int i = 0; i < 4; ++i) {
        float s = ps[mi][i], d = pd[mi][i];
        #pragma unroll
        for (int m = 1; m < 16; m <<= 1) { s += __shfl_xor(s, m); d += __shfl_xor(d, m); }
        if (lr == 0) {
          const int r = r0 + wr * 64 + mi * 16 + rr + i;
          // unique slot per (block, wave-column): no race
          av_s[((size_t)r * 2 + hd) * 4 + blk * 2 + wc] = s;
          av_d[((size_t)r * 2 + hd) * 4 + blk * 2 + wc] = d;
        }
      }
    }
  } else if (EPI == 7) {
    #pragma unroll
    for (int mi = 0; mi < 4; ++mi) {
      #pragma unroll
      for (int i = 0; i < 4; ++i) {
        float s = ps[mi][i];
        #pragma unroll
        for (int m = 1; m < 16; m <<= 1) s += __shfl_xor(s, m);
        if (lr == 0) {
          const int r = r0 + wr * 64 + mi * 16 + rr + i;
          av_s[((size_t)z * 1024 + r) * 16 + ((n0 >> 7) << 1) + wc] = s;  // unique slot
        }
      }
    }
  }
}

// ============ PV + attn-normalize fused: per bh ============
// O = (expS(bf16) x vt^T) / rowsum -> catb; AND normalized f32 attn written from
// the staged LDS tile (each thread re-reads its OWN staged chunks -> bit-identical
// to the old normk kernel, but saves the separate 67 MB Pbuf re-read + a launch).
__global__ __launch_bounds__(256)
void pv_k(const bfu* __restrict__ Pb, const bfu* __restrict__ vt,
          const float* __restrict__ rowsum16, bfu* __restrict__ catb,
          float* __restrict__ attn)
{
  __shared__ bfu As[128 * 32];
  __shared__ bfu Bs[64 * 32];
  const int tid = threadIdx.x;
  const int bh = blockIdx.z;
  const int r0 = blockIdx.y * 128;
  const bfu* Az = Pb + (size_t)bh * 1048576;
  const bfu* Bz = vt + (size_t)bh * 65536;
  const int w = tid >> 6, l = tid & 63;
  const int lr = l & 15, k8 = l >> 4;

  f32x4 acc[2][4] = {};

  const int s0c = swz(tid), s1c = swz(tid + 256);
  const int rA0 = r0 + (s0c >> 2), rA1 = r0 + (s1c >> 2);
  const bfu* ga0 = Az + (size_t)rA0 * 1024 + (s0c & 3) * 8;
  const bfu* ga1 = Az + (size_t)rA1 * 1024 + (s1c & 3) * 8;
  const bfu* gb0 = Bz + (size_t)(s0c >> 2) * 1024 + (s0c & 3) * 8;
  bfu* la0 = As + tid * 8;
  bfu* la1 = As + (tid + 256) * 8;
  bfu* lb0 = Bs + tid * 8;

  // per-staged-row inverse softmax denominators
  float sm0 = 0.f, sm1 = 0.f;
  #pragma unroll
  for (int j = 0; j < 16; ++j) {
    sm0 += rowsum16[((size_t)bh * 1024 + rA0) * 16 + j];
    sm1 += rowsum16[((size_t)bh * 1024 + rA1) * 16 + j];
  }
  const float invA0 = 1.f / sm0, invA1 = 1.f / sm1;
  float* aout0 = attn + ((size_t)bh * 1024 + rA0) * 1024 + (s0c & 3) * 8;
  float* aout1 = attn + ((size_t)bh * 1024 + rA1) * 1024 + (s1c & 3) * 8;

  for (int k0 = 0; k0 < 1024; k0 += 32) {
    __syncthreads();
    GLL16(ga0, la0); GLL16(ga1, la1); GLL16(gb0, lb0);
    ga0 += 32; ga1 += 32; gb0 += 32;
    __syncthreads();

    // normalized f32 attn from own staged chunks (same values normk produced)
    {
      uint4 u0 = *(const uint4*)la0;
      uint4 u1 = *(const uint4*)la1;
      float f0[8], f1[8];
      unpack8(u0, f0); unpack8(u1, f1);
      float4 o;
      o.x = f0[0]*invA0; o.y = f0[1]*invA0; o.z = f0[2]*invA0; o.w = f0[3]*invA0;
      *(float4*)(aout0 + k0) = o;
      o.x = f0[4]*invA0; o.y = f0[5]*invA0; o.z = f0[6]*invA0; o.w = f0[7]*invA0;
      *(float4*)(aout0 + k0 + 4) = o;
      o.x = f1[0]*invA1; o.y = f1[1]*invA1; o.z = f1[2]*invA1; o.w = f1[3]*invA1;
      *(float4*)(aout1 + k0) = o;
      o.x = f1[4]*invA1; o.y = f1[5]*invA1; o.z = f1[6]*invA1; o.w = f1[7]*invA1;
      *(float4*)(aout1 + k0 + 4) = o;
    }

    short8v af[2], bfr[4];
    #pragma unroll
    for (int mi = 0; mi < 2; ++mi) {
      const int R = w * 32 + mi * 16 + lr;
      af[mi] = *(const short8v*)(As + swz(R * 4 + k8) * 8);
    }
    #pragma unroll
    for (int ni = 0; ni < 4; ++ni) {
      const int R = ni * 16 + lr;
      bfr[ni] = *(const short8v*)(Bs + swz(R * 4 + k8) * 8);
    }
    #pragma unroll
    for (int mi = 0; mi < 2; ++mi)
      #pragma unroll
      for (int ni = 0; ni < 4; ++ni)
        acc[mi][ni] = __builtin_amdgcn_mfma_f32_16x16x32_bf16(af[mi], bfr[ni], acc[mi][ni], 0, 0, 0);
  }

  const int b = bh >> 1, h = bh & 1;
  const int rr = k8 * 4;
  #pragma unroll
  for (int mi = 0; mi < 2; ++mi) {
    #pragma unroll
    for (int i = 0; i < 4; ++i) {
      const int qn = r0 + w * 32 + mi * 16 + rr + i;
      float sm = 0.f;
      #pragma unroll
      for (int j = 0; j < 16; ++j) sm += rowsum16[((size_t)bh * 1024 + qn) * 16 + j];
      const float inv = 1.f / sm;
      #pragma unroll
      for (int ni = 0; ni < 4; ++ni) {
        const int d = ni * 16 + lr;
        catb[((size_t)(b * 1024 + qn)) * 256 + 128 + h * 64 + d] = f2b(acc[mi][ni][i] * inv);
      }
    }
  }
}

// ============ merged conversions: z<3 -> q/k/v f32->bf16; z==3 -> all weights transposed ============
__global__ __launch_bounds__(256)
void conv_all(const float* __restrict__ q, const float* __restrict__ k, const float* __restrict__ v,
              bfu* __restrict__ qo, bfu* __restrict__ ko, bfu* __restrict__ vo,
              const float* __restrict__ Wq, const float* __restrict__ Wk, const float* __restrict__ Wv,
              const float* __restrict__ Wfc, const float* __restrict__ g1W, const float* __restrict__ l1W,
              const float* __restrict__ g2W, const float* __restrict__ l2W, const float* __restrict__ g3W,
              const float* __restrict__ l3W, bfu* __restrict__ out)
{
  const int zz = blockIdx.y;
  if (zz < 3) {
    const int i = blockIdx.x * 256 + threadIdx.x;
    if (i >= NT * 64) return;
    const float* src = zz == 0 ? q : (zz == 1 ? k : v);
    bfu* dst = zz == 0 ? qo : (zz == 1 ? ko : vo);
    float4 x = ((const float4*)src)[i];
    uint2 o;
    o.x = (unsigned)f2b(x.x) | ((unsigned)f2b(x.y) << 16);
    o.y = (unsigned)f2b(x.z) | ((unsigned)f2b(x.w) << 16);
    ((uint2*)dst)[i] = o;
    return;
  }
  const int idx = blockIdx.x * 256 + threadIdx.x;
  const float* src; int kb, N, base; float sc = 1.f;
  if (idx < 98304)        { int wi = idx >> 15; base = wi << 15; src = wi == 0 ? Wq : (wi == 1 ? Wk : Wv); kb = 8; N = 128; if (wi == 0) sc = 0.125f; }
  else if (idx < 163840)  { base = 98304;  src = Wfc; kb = 8; N = 256; }
  else if (idx < 294912)  { base = 163840; src = g1W; kb = 8; N = 512; }
  else if (idx < 425984)  { base = 294912; src = l1W; kb = 8; N = 512; }
  else if (idx < 688128)  { base = 425984; src = g2W; kb = 9; N = 512; }
  else if (idx < 950272)  { base = 688128; src = l2W; kb = 9; N = 512; }
  else if (idx < 1081344) { base = 950272; src = g3W; kb = 9; N = 256; }
  else if (idx < 1146880) { base = 1081344; src = l3W; kb = 9; N = 128; }
  else return;
  const int local = idx - base;
  const int n = local >> kb, kk = local & ((1 << kb) - 1);
  out[idx] = f2b(src[(size_t)kk * N + n] * sc);
}

__global__ void zero_i(int* p, int n) {
  int i = blockIdx.x * 256 + threadIdx.x;
  if (i < n) p[i] = 0;
}

// ---------------- CSR build ----------------
__global__ void csr_count(const int* __restrict__ ei, int* __restrict__ deg) {
  int e = blockIdx.x * 256 + threadIdx.x;
  if (e >= ET) return;
  int s, d; edge_sd(ei, e, s, d);
  atomicAdd(&deg[d], 1);
}
__global__ __launch_bounds__(1024)
void csr_scan(const int* __restrict__ deg, int* __restrict__ rowptr, int* __restrict__ fillc) {
  __shared__ int sums[1024];
  const int t = threadIdx.x;
  const int base = t * 16;
  int loc[16]; int s = 0;
  #pragma unroll
  for (int k = 0; k < 16; ++k) { loc[k] = deg[base + k]; s += loc[k]; }
  sums[t] = s;
  __syncthreads();
  for (int off = 1; off < 1024; off <<= 1) {
    int v = (t >= off) ? sums[t - off] : 0;
    __syncthreads();
    sums[t] += v;
    __syncthreads();
  }
  int run = sums[t] - s;
  #pragma unroll
  for (int k = 0; k < 16; ++k) { rowptr[base + k] = run; fillc[base + k] = run; run += loc[k]; }
  if (t == 1023) rowptr[NT] = sums[1023];
}
// stores SRC node directly (not edge id)
__global__ void csr_fill(const int* __restrict__ ei, int* __restrict__ fillc, int* __restrict__ srcs) {
  int e = blockIdx.x * 256 + threadIdx.x;
  if (e >= ET) return;
  int s, d; edge_sd(ei, e, s, d);
  int pos = atomicAdd(&fillc[d], 1);
  srcs[pos] = s;
}

// ---------------- fused GAT softmax + aggregation ----------------
// partial layout: [node][head(2)][blk(2)][wc(2)] = 8 f32 per node
template<int CT, int NBLK>  // CT: 512 (layers 1/2) or 256 (layer 3); NBLK: col-blocks/head
__global__ __launch_bounds__(256)
void aggf_k(const int* __restrict__ rowptr, const int* __restrict__ srcs,
            const float* __restrict__ avsp, const float* __restrict__ avdp,
            const bfu* __restrict__ h, bfu* __restrict__ agg)
{
  const int n = blockIdx.x, tid = threadIdx.x;
  float ad0 = avdp[(size_t)n * 8 + 0] + avdp[(size_t)n * 8 + 1];
  float ad1 = avdp[(size_t)n * 8 + 4] + avdp[(size_t)n * 8 + 5];
  if (NBLK > 1) {
    ad0 += avdp[(size_t)n * 8 + 2] + avdp[(size_t)n * 8 + 3];
    ad1 += avdp[(size_t)n * 8 + 6] + avdp[(size_t)n * 8 + 7];
  }
  float a0 = 0.f, a1 = 0.f, sum0 = 0.f, sum1 = 0.f;
  const int beg = rowptr[n], end = rowptr[n + 1];
  for (int idx = beg; idx < end; ++idx) {
    const int s = srcs[idx];
    float as0 = avsp[(size_t)s * 8 + 0] + avsp[(size_t)s * 8 + 1];
    float as1 = avsp[(size_t)s * 8 + 4] + avsp[(size_t)s * 8 + 5];
    if (NBLK > 1) {
      as0 += avsp[(size_t)s * 8 + 2] + avsp[(size_t)s * 8 + 3];
      as1 += avsp[(size_t)s * 8 + 6] + avsp[(size_t)s * 8 + 7];
    }
    float al0 = as0 + ad0; al0 = al0 > 0.f ? al0 : 0.2f * al0;
    float al1 = as1 + ad1; al1 = al1 > 0.f ? al1 : 0.2f * al1;
    const float e0 = expf(al0), e1 = expf(al1);
    sum0 += e0; sum1 += e1;
    if (CT == 512) {
      a0 = fmaf(e0, b2f(h[(size_t)s * 512 + tid]), a0);
      a1 = fmaf(e1, b2f(h[(size_t)s * 512 + 256 + tid]), a1);
    } else {
      const float ev = tid < 128 ? e0 : e1;
      a0 = fmaf(ev, b2f(h[(size_t)s * 256 + tid]), a0);
    }
  }
  if (CT == 512) {
    agg[(size_t)n * 512 + tid] = f2b(a0 / (sum0 + 1e-16f));
    agg[(size_t)n * 512 + 256 + tid] = f2b(a1 / (sum1 + 1e-16f));
  } else {
    const float sv = tid < 128 ? sum0 : sum1;
    agg[(size_t)n * 256 + tid] = f2b(a0 / (sv + 1e-16f));
  }
}

// ---------------- LayerNorm over 256, write f32 y ----------------
__global__ __launch_bounds__(256)
void ln_k(const float* __restrict__ x, const float* __restrict__ g, const float* __restrict__ bta,
          float* __restrict__ y)
{
  const int r = blockIdx.x, tid = threadIdx.x;
  float v = x[(size_t)r * 256 + tid];
  float s = v;
  #pragma unroll
  for (int off = 32; off; off >>= 1) s += __shfl_xor(s, off);
  __shared__ float red[4], red2[4];
  const int w = tid >> 6, lane = tid & 63;
  if (lane == 0) red[w] = s;
  __syncthreads();
  float mu = (red[0] + red[1] + red[2] + red[3]) * (1.f / 256.f);
  float dv = v - mu;
  float q2 = dv * dv;
  #pragma unroll
  for (int off = 32; off; off >>= 1) q2 += __shfl_xor(q2, off);
  if (lane == 0) red2[w] = q2;
  __syncthreads();
  float var = (red2[0] + red2[1] + red2[2] + red2[3]) * (1.f / 256.f);
  y[(size_t)r * 256 + tid] = dv * rsqrtf(var + 1e-6f) * g[tid] + bta[tid];
}

extern "C" void kernel_launch(void* const* d_in, const int* in_sizes, int n_in,
                              void* d_out, int out_size, void* d_ws, size_t ws_size,
                              hipStream_t stream)
{
  const float* q   = (const float*)d_in[0];
  const float* kin = (const float*)d_in[1];
  const float* vin = (const float*)d_in[2];
  const int*   ei  = (const int*)d_in[3];
  const float* Wq  = (const float*)d_in[4];
  const float* Wk  = (const float*)d_in[5];
  const float* Wv  = (const float*)d_in[6];
  const float* Wfc = (const float*)d_in[7];
  const float* g1W = (const float*)d_in[8],  *g1as = (const float*)d_in[9],  *g1ad = (const float*)d_in[10];
  const float* l1W = (const float*)d_in[12], *l1b = (const float*)d_in[13], *g1b = (const float*)d_in[11];
  const float* g2W = (const float*)d_in[14], *g2as = (const float*)d_in[15], *g2ad = (const float*)d_in[16], *g2b = (const float*)d_in[17];
  const float* l2W = (const float*)d_in[18], *l2b = (const float*)d_in[19];
  const float* g3W = (const float*)d_in[20], *g3as = (const float*)d_in[21], *g3ad = (const float*)d_in[22], *g3b = (const float*)d_in[23];
  const float* l3W = (const float*)d_in[24], *l3b = (const float*)d_in[25];
  const float* lng = (const float*)d_in[26], *lnb = (const float*)d_in[27];

  // ---- d_out regions (f32 output) ----
  float* ybuf = (float*)d_out;                          // y: NT*256 f32
  float* attn_out = ybuf + (size_t)NT * 256;            // attn: 32M f32 = 134.2 MB
  bfu* catb = (bfu*)d_out;                              // bf16 [NT][256] in y region

  // GAT scratch in attn region (dead before pv_k writes attn over it)
  char* ap = (char*)attn_out;
  auto take_a = [&](size_t bytes) -> void* {
    void* r = (void*)ap; ap += (bytes + 255) & ~(size_t)255; return r;
  };
  bfu* q_bf = (bfu*)take_a((size_t)NT * 256 * 2);   // NOTE: q_bf/k_bf/v_bf contiguous (EPI 8 relies on stride NT*256)
  bfu* k_bf = (bfu*)take_a((size_t)NT * 256 * 2);
  bfu* v_bf = (bfu*)take_a((size_t)NT * 256 * 2);
  bfu* aggb  = (bfu*)take_a((size_t)NT * 512 * 2);
  float* avsp = (float*)take_a((size_t)NT * 8 * 4);  // alpha-src partials [r][hd][blk][wc]
  float* avdp = (float*)take_a((size_t)NT * 8 * 4);  // alpha-dst partials
  int* deg    = (int*)take_a((size_t)NT * 4);
  int* rowptr = (int*)take_a((size_t)(NT + 1) * 4);
  int* fillc  = (int*)take_a((size_t)NT * 4);
  int* srcs   = (int*)take_a((size_t)ET * 4);

  // ---- d_ws (~117 MB) ----
  char* p = (char*)d_ws;
  auto take = [&](size_t bytes) -> void* {
    void* r = (void*)p; p += (bytes + 255) & ~(size_t)255; return r;
  };
  bfu* hbuf = (bfu*)take((size_t)NT * 512 * 2);
  bfu* x1   = (bfu*)take((size_t)NT * 512 * 2);
  bfu* x2   = (bfu*)take((size_t)NT * 512 * 2);
  bfu* wall = (bfu*)take((size_t)1146880 * 2);               // all converted weights
  bfu* Pbuf = (bfu*)take((size_t)32 * 1048576 * 2);          // bf16 expS [32][1024][1024]
  float* rowsum16 = (float*)take((size_t)32 * 1024 * 16 * 4);// attn row-sum partials [bh][r][16]

  bfu* WqT  = wall;                 // WqT/WkT/WvT contiguous, stride 32768 (EPI 8)
  bfu* WfcT = wall + 98304;
  bfu* g1Wt = wall + 163840;
  bfu* l1Wt = wall + 294912;
  bfu* g2Wt = wall + 425984;
  bfu* l2Wt = wall + 688128;
  bfu* g3Wt = wall + 950272;
  bfu* l3Wt = wall + 1081344;

  // hbuf dead after layer-3 agg -> attention operand aliases
  bfu* qh2  = hbuf;                            // [32][1024][64] (EPI 8 z=0 base)
  bfu* khb2 = hbuf + (size_t)2 * 1024 * 1024;
  bfu* vt   = hbuf + (size_t)4 * 1024 * 1024;  // [32][64][1024]
  float* prelng = (float*)x1;                  // x1 dead after layer-2 gemms

  const int EB = (ET + 255) / 256;
  const long long zs = 0;
  #define NOAL nullptr, nullptr, nullptr, nullptr

  // conversions (fully merged: q/k/v bf16 + all weight transposes)
  conv_all<<<dim3(4480, 4), 256, 0, stream>>>(q, kin, vin, q_bf, k_bf, v_bf,
                                              Wq, Wk, Wv, Wfc, g1W, l1W, g2W, l2W, g3W, l3W, wall);

  // CSR build (srcs stored directly)
  zero_i<<<(NT + 255) / 256, 256, 0, stream>>>(deg, NT);
  csr_count<<<EB, 256, 0, stream>>>(ei, deg);
  csr_scan<<<1, 1024, 0, stream>>>(deg, rowptr, fillc);
  csr_fill<<<EB, 256, 0, stream>>>(ei, fillc, srcs);

  // ---- GAT layer 1 ----
  mgemm<0><<<dim3(4, 128), 256, 0, stream>>>(q_bf, 256, zs, g1Wt, 256, zs, 256, hbuf, nullptr, 512, zs, nullptr, nullptr, nullptr, 0, nullptr, g1as, g1ad, avsp, avdp);
  aggf_k<512, 2><<<NT, 256, 0, stream>>>(rowptr, srcs, avsp, avdp, hbuf, aggb);
  mgemm<1><<<dim3(4, 128), 256, 0, stream>>>(q_bf, 256, zs, l1Wt, 256, zs, 256, x1, nullptr, 512, zs, l1b, g1b, aggb, 512, nullptr, NOAL);

  // ---- GAT layer 2 ----
  mgemm<0><<<dim3(4, 128), 256, 0, stream>>>(x1, 512, zs, g2Wt, 512, zs, 512, hbuf, nullptr, 512, zs, nullptr, nullptr, nullptr, 0, nullptr, g2as, g2ad, avsp, avdp);
  aggf_k<512, 2><<<NT, 256, 0, stream>>>(rowptr, srcs, avsp, avdp, hbuf, aggb);
  mgemm<1><<<dim3(4, 128), 256, 0, stream>>>(x1, 512, zs, l2Wt, 512, zs, 512, x2, nullptr, 512, zs, l2b, g2b, aggb, 512, nullptr, NOAL);
  // x1 now dead.

  // ---- GAT layer 3 -> catb[:,0:128] ----
  mgemm<0><<<dim3(2, 128), 256, 0, stream>>>(x2, 512, zs, g3Wt, 512, zs, 512, hbuf, nullptr, 256, zs, nullptr, nullptr, nullptr, 0, nullptr, g3as, g3ad, avsp, avdp);
  aggf_k<256, 1><<<NT, 256, 0, stream>>>(rowptr, srcs, avsp, avdp, hbuf, aggb);
  mgemm<2><<<dim3(1, 128), 256, 0, stream>>>(x2, 512, zs, l3Wt, 512, zs, 512, catb, nullptr, 256, zs, l3b, g3b, aggb, 256, nullptr, NOAL);
  // hbuf now dead -> qh2/khb2/vt.

  // ---- q/k/v projections, batched over z (head-split layouts) ----
  mgemm<8><<<dim3(1, 128, 3), 256, 0, stream>>>(q_bf, 256, (long long)NT * 256, WqT, 256, 32768LL, 256, qh2, nullptr, 0, zs, nullptr, nullptr, nullptr, 0, nullptr, NOAL);

  // ---- attention: expS bf16 + rowsum partials -> PV (writes normalized f32 attn too) ----
  mgemm<7><<<dim3(8, 8, 32), 256, 0, stream>>>(qh2, 64, 65536LL, khb2, 64, 65536LL, 64, Pbuf, nullptr, 1024, 1048576LL, nullptr, nullptr, nullptr, 0, nullptr, nullptr, nullptr, rowsum16, nullptr);
  pv_k<<<dim3(1, 8, 32), 256, 0, stream>>>(Pbuf, vt, rowsum16, catb, attn_out);

  // ---- final FC + residual + LN ----
  mgemm<3><<<dim3(2, 128), 256, 0, stream>>>(catb, 256, zs, WfcT, 256, zs, 256, nullptr, prelng, 256, zs, nullptr, nullptr, nullptr, 0, q, NOAL);
  ln_k<<<NT, 256, 0, stream>>>(prelng, lng, lnb, ybuf);
}

// Round 17
// 461.497 us; speedup vs baseline: 1.0951x; 1.0371x over previous
//
#include <hip/hip_runtime.h>

#define BSZ 16
#define NNODE 1024
#define NT (BSZ*NNODE)      // 16384 total nodes
#define EG 131072            // graph edges (before self loops)
#define ET (EG+NT)           // 147456 edges incl self loops

typedef unsigned short bfu;  // raw bf16
typedef __attribute__((ext_vector_type(8))) short short8v;   // 8 bf16 (4 VGPRs)
typedef __attribute__((ext_vector_type(4))) float f32x4;     // MFMA accum

typedef __attribute__((address_space(1))) const unsigned gU32;
typedef __attribute__((address_space(3))) unsigned lU32;
#define GLL16(gp, lp) __builtin_amdgcn_global_load_lds((gU32*)(gp), (lU32*)(lp), 16, 0, 0)

__device__ __forceinline__ float b2f(unsigned u) { return __uint_as_float(u << 16); }
__device__ __forceinline__ bfu f2b(float f) {
  unsigned u = __float_as_uint(f);
  u += 0x7fffu + ((u >> 16) & 1u);
  return (bfu)(u >> 16);
}
__device__ __forceinline__ void unpack8(uint4 u, float* f) {
  f[0] = b2f(u.x & 0xffffu); f[1] = b2f(u.x >> 16);
  f[2] = b2f(u.y & 0xffffu); f[3] = b2f(u.y >> 16);
  f[4] = b2f(u.z & 0xffffu); f[5] = b2f(u.z >> 16);
  f[6] = b2f(u.w & 0xffffu); f[7] = b2f(u.w >> 16);
}
__device__ __forceinline__ void edge_sd(const int* __restrict__ ei, int e, int& s, int& d) {
  if (e < EG) { s = ei[e]; d = ei[EG + e]; } else { s = e - EG; d = e - EG; }
}
// chunk swizzle (involution): spreads the 4 k8-chunks of each row across bank groups
__device__ __forceinline__ int swz(int c) {
  int r = c >> 2;
  return (c & ~3) | ((c & 3) ^ ((r & 3) ^ ((r >> 2) & 3)));
}

// ============ MFMA GEMM: C[M,N] = A[M,K](bf16) x Bt[N,K](bf16)^T ============
// 128x128 tile, BK=32, 4 waves (2x2 of 64x64), 16x16x32 bf16, global_load_lds staging.
// XCD-aware bijective block swizzle (grid x*y always divisible by 8).
// EPI 0: bf16 out = acc; GAT-alpha partials STORED to av_s/av_d[r][hd][blk][wc]
// EPI 1: bf16 out = elu(acc + b1[c] + b2[c] + agg[r*aggld+c])
// EPI 2: bf16 out = acc + b1[c] + b2[c] + 0.5*(agg[..c]+agg[..128+c])   (layer3 head-mean)
// EPI 3: f32 out  = acc + resid[r*ldo+c]                                 (pre-LN)
// EPI 7: bf16 out = exp(acc) (z-batched); row-sum partials STORED [z][r][blk][wc] (16)
// EPI 8: batched qkv projections: z<2 -> [bh][node][64] at z*2M; z==2 -> vt [bh][d][node] at 4M
template<int EPI>
__global__ __launch_bounds__(256)
void mgemm(const bfu* __restrict__ A, int lda, long long sA,
           const bfu* __restrict__ Bt, int ldb, long long sB,
           int K,
           bfu* __restrict__ outb, float* __restrict__ outf, int ldo, long long sO,
           const float* __restrict__ b1, const float* __restrict__ b2,
           const bfu* __restrict__ agg, int aggld,
           const float* __restrict__ resid,
           const float* __restrict__ asrc, const float* __restrict__ adst,
           float* __restrict__ av_s, float* __restrict__ av_d)
{
  __shared__ bfu As[128 * 32];
  __shared__ bfu Bs[128 * 32];
  const int tid = threadIdx.x;
  const int z = blockIdx.z;
  // XCD-aware bijective swizzle of the flattened xy block id (nwg % 8 == 0 always here)
  const int nwg = gridDim.x * gridDim.y;
  const int orig = blockIdx.y * gridDim.x + blockIdx.x;
  const int cpx = nwg >> 3;
  const int sid = (orig & 7) * cpx + (orig >> 3);
  const int bx = sid % gridDim.x, by = sid / gridDim.x;
  const int n0 = bx * 128, r0 = by * 128;
  const bfu* Az = A + (size_t)z * sA;
  const bfu* Bz = Bt + (size_t)z * sB;

  const int w = tid >> 6, l = tid & 63;
  const int wr = w >> 1, wc = w & 1;
  const int lr = l & 15;
  const int k8 = l >> 4;

  f32x4 acc[4][4] = {};

  const int s0c = swz(tid), s1c = swz(tid + 256);
  const bfu* ga0 = Az + (size_t)(r0 + (s0c >> 2)) * lda + (s0c & 3) * 8;
  const bfu* ga1 = Az + (size_t)(r0 + (s1c >> 2)) * lda + (s1c & 3) * 8;
  const bfu* gb0 = Bz + (size_t)(n0 + (s0c >> 2)) * ldb + (s0c & 3) * 8;
  const bfu* gb1 = Bz + (size_t)(n0 + (s1c >> 2)) * ldb + (s1c & 3) * 8;
  bfu* la0 = As + tid * 8;
  bfu* la1 = As + (tid + 256) * 8;
  bfu* lb0 = Bs + tid * 8;
  bfu* lb1 = Bs + (tid + 256) * 8;

  for (int k0 = 0; k0 < K; k0 += 32) {
    __syncthreads();
    GLL16(ga0, la0); GLL16(ga1, la1);
    GLL16(gb0, lb0); GLL16(gb1, lb1);
    ga0 += 32; ga1 += 32; gb0 += 32; gb1 += 32;
    __syncthreads();
    short8v af[4], bfr[4];
    #pragma unroll
    for (int mi = 0; mi < 4; ++mi) {
      const int R = wr * 64 + mi * 16 + lr;
      af[mi] = *(const short8v*)(As + swz(R * 4 + k8) * 8);
    }
    #pragma unroll
    for (int ni = 0; ni < 4; ++ni) {
      const int R = wc * 64 + ni * 16 + lr;
      bfr[ni] = *(const short8v*)(Bs + swz(R * 4 + k8) * 8);
    }
    #pragma unroll
    for (int mi = 0; mi < 4; ++mi)
      #pragma unroll
      for (int ni = 0; ni < 4; ++ni)
        acc[mi][ni] = __builtin_amdgcn_mfma_f32_16x16x32_bf16(af[mi], bfr[ni], acc[mi][ni], 0, 0, 0);
  }

  const int rr = k8 * 4;
  float ps[4][4], pd[4][4];
  if (EPI == 0 || EPI == 7) {
    #pragma unroll
    for (int mi = 0; mi < 4; ++mi)
      #pragma unroll
      for (int i = 0; i < 4; ++i) { ps[mi][i] = 0.f; pd[mi][i] = 0.f; }
  }

  #pragma unroll
  for (int mi = 0; mi < 4; ++mi) {
    #pragma unroll
    for (int ni = 0; ni < 4; ++ni) {
      #pragma unroll
      for (int i = 0; i < 4; ++i) {
        const int r = r0 + wr * 64 + mi * 16 + rr + i;
        const int cc = n0 + wc * 64 + ni * 16 + lr;
        float val = acc[mi][ni][i];
        if (EPI == 0) {
          outb[(size_t)r * ldo + cc] = f2b(val);
          ps[mi][i] = fmaf(val, asrc[cc], ps[mi][i]);
          pd[mi][i] = fmaf(val, adst[cc], pd[mi][i]);
        } else if (EPI == 1) {
          val += b1[cc] + b2[cc] + b2f(agg[(size_t)r * aggld + cc]);
          val = val > 0.f ? val : expm1f(val);
          outb[(size_t)r * ldo + cc] = f2b(val);
        } else if (EPI == 2) {
          val += b1[cc] + b2[cc]
               + 0.5f * (b2f(agg[(size_t)r * aggld + cc]) + b2f(agg[(size_t)r * aggld + 128 + cc]));
          outb[(size_t)r * ldo + cc] = f2b(val);
        } else if (EPI == 3) {
          outf[(size_t)r * ldo + cc] = val + resid[(size_t)r * ldo + cc];
        } else if (EPI == 7) {
          float e = expf(val);
          outb[(size_t)z * sO + (size_t)r * ldo + cc] = f2b(e);
          ps[mi][i] += e;
        } else { // EPI == 8: batched q/k/v projections
          if (z < 2) {
            outb[(size_t)z * 2097152 + ((size_t)((r >> 10) * 2 + (cc >> 6))) * 65536
                 + (size_t)(r & 1023) * 64 + (cc & 63)] = f2b(val);
          } else {
            outb[4194304 + ((size_t)((r >> 10) * 2 + (cc >> 6))) * 65536
                 + (size_t)(cc & 63) * 1024 + (r & 1023)] = f2b(val);
          }
        }
      }
    }
  }

  if (EPI == 0) {
    const int half = ldo >> 1;
    const int hd = n0 / half;                 // head, uniform per block
    const int blk = (n0 & (half - 1)) >> 7;   // block index within head (0 or 1)
    #pragma unroll
    for (int mi = 0; mi < 4; ++mi) {
      #pragma unroll
      for (int i = 0; i < 4; ++i) {
        float s = ps[mi][i], d = pd[mi][i];
        #pragma unroll
        for (int m = 1; m < 16; m <<= 1) { s += __shfl_xor(s, m); d += __shfl_xor(d, m); }
        if (lr == 0) {
          const int r = r0 + wr * 64 + mi * 16 + rr + i;
          // unique slot per (block, wave-column): no race
          av_s[((size_t)r * 2 + hd) * 4 + blk * 2 + wc] = s;
          av_d[((size_t)r * 2 + hd) * 4 + blk * 2 + wc] = d;
        }
      }
    }
  } else if (EPI == 7) {
    #pragma unroll
    for (int mi = 0; mi < 4; ++mi) {
      #pragma unroll
      for (int i = 0; i < 4; ++i) {
        float s = ps[mi][i];
        #pragma unroll
        for (int m = 1; m < 16; m <<= 1) s += __shfl_xor(s, m);
        if (lr == 0) {
          const int r = r0 + wr * 64 + mi * 16 + rr + i;
          av_s[((size_t)z * 1024 + r) * 16 + ((n0 >> 7) << 1) + wc] = s;  // unique slot
        }
      }
    }
  }
}

// ============ PV + attn-normalize fused: per bh ============
__global__ __launch_bounds__(256)
void pv_k(const bfu* __restrict__ Pb, const bfu* __restrict__ vt,
          const float* __restrict__ rowsum16, bfu* __restrict__ catb,
          float* __restrict__ attn)
{
  __shared__ bfu As[128 * 32];
  __shared__ bfu Bs[64 * 32];
  const int tid = threadIdx.x;
  const int bh = blockIdx.z;
  const int r0 = blockIdx.y * 128;
  const bfu* Az = Pb + (size_t)bh * 1048576;
  const bfu* Bz = vt + (size_t)bh * 65536;
  const int w = tid >> 6, l = tid & 63;
  const int lr = l & 15, k8 = l >> 4;

  f32x4 acc[2][4] = {};

  const int s0c = swz(tid), s1c = swz(tid + 256);
  const int rA0 = r0 + (s0c >> 2), rA1 = r0 + (s1c >> 2);
  const bfu* ga0 = Az + (size_t)rA0 * 1024 + (s0c & 3) * 8;
  const bfu* ga1 = Az + (size_t)rA1 * 1024 + (s1c & 3) * 8;
  const bfu* gb0 = Bz + (size_t)(s0c >> 2) * 1024 + (s0c & 3) * 8;
  bfu* la0 = As + tid * 8;
  bfu* la1 = As + (tid + 256) * 8;
  bfu* lb0 = Bs + tid * 8;

  float sm0 = 0.f, sm1 = 0.f;
  #pragma unroll
  for (int j = 0; j < 16; ++j) {
    sm0 += rowsum16[((size_t)bh * 1024 + rA0) * 16 + j];
    sm1 += rowsum16[((size_t)bh * 1024 + rA1) * 16 + j];
  }
  const float invA0 = 1.f / sm0, invA1 = 1.f / sm1;
  float* aout0 = attn + ((size_t)bh * 1024 + rA0) * 1024 + (s0c & 3) * 8;
  float* aout1 = attn + ((size_t)bh * 1024 + rA1) * 1024 + (s1c & 3) * 8;

  for (int k0 = 0; k0 < 1024; k0 += 32) {
    __syncthreads();
    GLL16(ga0, la0); GLL16(ga1, la1); GLL16(gb0, lb0);
    ga0 += 32; ga1 += 32; gb0 += 32;
    __syncthreads();

    {
      uint4 u0 = *(const uint4*)la0;
      uint4 u1 = *(const uint4*)la1;
      float f0[8], f1[8];
      unpack8(u0, f0); unpack8(u1, f1);
      float4 o;
      o.x = f0[0]*invA0; o.y = f0[1]*invA0; o.z = f0[2]*invA0; o.w = f0[3]*invA0;
      *(float4*)(aout0 + k0) = o;
      o.x = f0[4]*invA0; o.y = f0[5]*invA0; o.z = f0[6]*invA0; o.w = f0[7]*invA0;
      *(float4*)(aout0 + k0 + 4) = o;
      o.x = f1[0]*invA1; o.y = f1[1]*invA1; o.z = f1[2]*invA1; o.w = f1[3]*invA1;
      *(float4*)(aout1 + k0) = o;
      o.x = f1[4]*invA1; o.y = f1[5]*invA1; o.z = f1[6]*invA1; o.w = f1[7]*invA1;
      *(float4*)(aout1 + k0 + 4) = o;
    }

    short8v af[2], bfr[4];
    #pragma unroll
    for (int mi = 0; mi < 2; ++mi) {
      const int R = w * 32 + mi * 16 + lr;
      af[mi] = *(const short8v*)(As + swz(R * 4 + k8) * 8);
    }
    #pragma unroll
    for (int ni = 0; ni < 4; ++ni) {
      const int R = ni * 16 + lr;
      bfr[ni] = *(const short8v*)(Bs + swz(R * 4 + k8) * 8);
    }
    #pragma unroll
    for (int mi = 0; mi < 2; ++mi)
      #pragma unroll
      for (int ni = 0; ni < 4; ++ni)
        acc[mi][ni] = __builtin_amdgcn_mfma_f32_16x16x32_bf16(af[mi], bfr[ni], acc[mi][ni], 0, 0, 0);
  }

  const int b = bh >> 1, h = bh & 1;
  const int rr = k8 * 4;
  #pragma unroll
  for (int mi = 0; mi < 2; ++mi) {
    #pragma unroll
    for (int i = 0; i < 4; ++i) {
      const int qn = r0 + w * 32 + mi * 16 + rr + i;
      float sm = 0.f;
      #pragma unroll
      for (int j = 0; j < 16; ++j) sm += rowsum16[((size_t)bh * 1024 + qn) * 16 + j];
      const float inv = 1.f / sm;
      #pragma unroll
      for (int ni = 0; ni < 4; ++ni) {
        const int d = ni * 16 + lr;
        catb[((size_t)(b * 1024 + qn)) * 256 + 128 + h * 64 + d] = f2b(acc[mi][ni][i] * inv);
      }
    }
  }
}

// ============ merged conversions: z<3 -> q/k/v f32->bf16; z==3 -> weights; z==4 -> zero deg ============
__global__ __launch_bounds__(256)
void conv_all(const float* __restrict__ q, const float* __restrict__ k, const float* __restrict__ v,
              bfu* __restrict__ qo, bfu* __restrict__ ko, bfu* __restrict__ vo,
              const float* __restrict__ Wq, const float* __restrict__ Wk, const float* __restrict__ Wv,
              const float* __restrict__ Wfc, const float* __restrict__ g1W, const float* __restrict__ l1W,
              const float* __restrict__ g2W, const float* __restrict__ l2W, const float* __restrict__ g3W,
              const float* __restrict__ l3W, bfu* __restrict__ out, int* __restrict__ deg)
{
  const int zz = blockIdx.y;
  if (zz < 3) {
    const int i = blockIdx.x * 256 + threadIdx.x;
    if (i >= NT * 64) return;
    const float* src = zz == 0 ? q : (zz == 1 ? k : v);
    bfu* dst = zz == 0 ? qo : (zz == 1 ? ko : vo);
    float4 x = ((const float4*)src)[i];
    uint2 o;
    o.x = (unsigned)f2b(x.x) | ((unsigned)f2b(x.y) << 16);
    o.y = (unsigned)f2b(x.z) | ((unsigned)f2b(x.w) << 16);
    ((uint2*)dst)[i] = o;
    return;
  }
  if (zz == 4) {
    const int i = blockIdx.x * 256 + threadIdx.x;
    if (i < NT) deg[i] = 0;
    return;
  }
  const int idx = blockIdx.x * 256 + threadIdx.x;
  const float* src; int kb, N, base; float sc = 1.f;
  if (idx < 98304)        { int wi = idx >> 15; base = wi << 15; src = wi == 0 ? Wq : (wi == 1 ? Wk : Wv); kb = 8; N = 128; if (wi == 0) sc = 0.125f; }
  else if (idx < 163840)  { base = 98304;  src = Wfc; kb = 8; N = 256; }
  else if (idx < 294912)  { base = 163840; src = g1W; kb = 8; N = 512; }
  else if (idx < 425984)  { base = 294912; src = l1W; kb = 8; N = 512; }
  else if (idx < 688128)  { base = 425984; src = g2W; kb = 9; N = 512; }
  else if (idx < 950272)  { base = 688128; src = l2W; kb = 9; N = 512; }
  else if (idx < 1081344) { base = 950272; src = g3W; kb = 9; N = 256; }
  else if (idx < 1146880) { base = 1081344; src = l3W; kb = 9; N = 128; }
  else return;
  const int local = idx - base;
  const int n = local >> kb, kk = local & ((1 << kb) - 1);
  out[idx] = f2b(src[(size_t)kk * N + n] * sc);
}

// ---------------- CSR build ----------------
__global__ void csr_count(const int* __restrict__ ei, int* __restrict__ deg) {
  int e = blockIdx.x * 256 + threadIdx.x;
  if (e >= ET) return;
  int s, d; edge_sd(ei, e, s, d);
  atomicAdd(&deg[d], 1);
}
__global__ __launch_bounds__(1024)
void csr_scan(const int* __restrict__ deg, int* __restrict__ rowptr, int* __restrict__ fillc) {
  __shared__ int sums[1024];
  const int t = threadIdx.x;
  const int base = t * 16;
  int loc[16]; int s = 0;
  #pragma unroll
  for (int k = 0; k < 16; ++k) { loc[k] = deg[base + k]; s += loc[k]; }
  sums[t] = s;
  __syncthreads();
  for (int off = 1; off < 1024; off <<= 1) {
    int v = (t >= off) ? sums[t - off] : 0;
    __syncthreads();
    sums[t] += v;
    __syncthreads();
  }
  int run = sums[t] - s;
  #pragma unroll
  for (int k = 0; k < 16; ++k) { rowptr[base + k] = run; fillc[base + k] = run; run += loc[k]; }
  if (t == 1023) rowptr[NT] = sums[1023];
}
// stores SRC node directly (not edge id)
__global__ void csr_fill(const int* __restrict__ ei, int* __restrict__ fillc, int* __restrict__ srcs) {
  int e = blockIdx.x * 256 + threadIdx.x;
  if (e >= ET) return;
  int s, d; edge_sd(ei, e, s, d);
  int pos = atomicAdd(&fillc[d], 1);
  srcs[pos] = s;
}

// ---------------- fused GAT softmax + aggregation ----------------
// partial layout: [node][head(2)][blk(2)][wc(2)] = 8 f32 per node
template<int CT, int NBLK>
__global__ __launch_bounds__(256)
void aggf_k(const int* __restrict__ rowptr, const int* __restrict__ srcs,
            const float* __restrict__ avsp, const float* __restrict__ avdp,
            const bfu* __restrict__ h, bfu* __restrict__ agg)
{
  const int n = blockIdx.x, tid = threadIdx.x;
  float ad0 = avdp[(size_t)n * 8 + 0] + avdp[(size_t)n * 8 + 1];
  float ad1 = avdp[(size_t)n * 8 + 4] + avdp[(size_t)n * 8 + 5];
  if (NBLK > 1) {
    ad0 += avdp[(size_t)n * 8 + 2] + avdp[(size_t)n * 8 + 3];
    ad1 += avdp[(size_t)n * 8 + 6] + avdp[(size_t)n * 8 + 7];
  }
  float a0 = 0.f, a1 = 0.f, sum0 = 0.f, sum1 = 0.f;
  const int beg = rowptr[n], end = rowptr[n + 1];
  for (int idx = beg; idx < end; ++idx) {
    const int s = srcs[idx];
    float as0 = avsp[(size_t)s * 8 + 0] + avsp[(size_t)s * 8 + 1];
    float as1 = avsp[(size_t)s * 8 + 4] + avsp[(size_t)s * 8 + 5];
    if (NBLK > 1) {
      as0 += avsp[(size_t)s * 8 + 2] + avsp[(size_t)s * 8 + 3];
      as1 += avsp[(size_t)s * 8 + 6] + avsp[(size_t)s * 8 + 7];
    }
    float al0 = as0 + ad0; al0 = al0 > 0.f ? al0 : 0.2f * al0;
    float al1 = as1 + ad1; al1 = al1 > 0.f ? al1 : 0.2f * al1;
    const float e0 = expf(al0), e1 = expf(al1);
    sum0 += e0; sum1 += e1;
    if (CT == 512) {
      a0 = fmaf(e0, b2f(h[(size_t)s * 512 + tid]), a0);
      a1 = fmaf(e1, b2f(h[(size_t)s * 512 + 256 + tid]), a1);
    } else {
      const float ev = tid < 128 ? e0 : e1;
      a0 = fmaf(ev, b2f(h[(size_t)s * 256 + tid]), a0);
    }
  }
  if (CT == 512) {
    agg[(size_t)n * 512 + tid] = f2b(a0 / (sum0 + 1e-16f));
    agg[(size_t)n * 512 + 256 + tid] = f2b(a1 / (sum1 + 1e-16f));
  } else {
    const float sv = tid < 128 ? sum0 : sum1;
    agg[(size_t)n * 256 + tid] = f2b(a0 / (sv + 1e-16f));
  }
}

// ---------------- LayerNorm over 256, write f32 y ----------------
__global__ __launch_bounds__(256)
void ln_k(const float* __restrict__ x, const float* __restrict__ g, const float* __restrict__ bta,
          float* __restrict__ y)
{
  const int r = blockIdx.x, tid = threadIdx.x;
  float v = x[(size_t)r * 256 + tid];
  float s = v;
  #pragma unroll
  for (int off = 32; off; off >>= 1) s += __shfl_xor(s, off);
  __shared__ float red[4], red2[4];
  const int w = tid >> 6, lane = tid & 63;
  if (lane == 0) red[w] = s;
  __syncthreads();
  float mu = (red[0] + red[1] + red[2] + red[3]) * (1.f / 256.f);
  float dv = v - mu;
  float q2 = dv * dv;
  #pragma unroll
  for (int off = 32; off; off >>= 1) q2 += __shfl_xor(q2, off);
  if (lane == 0) red2[w] = q2;
  __syncthreads();
  float var = (red2[0] + red2[1] + red2[2] + red2[3]) * (1.f / 256.f);
  y[(size_t)r * 256 + tid] = dv * rsqrtf(var + 1e-6f) * g[tid] + bta[tid];
}

extern "C" void kernel_launch(void* const* d_in, const int* in_sizes, int n_in,
                              void* d_out, int out_size, void* d_ws, size_t ws_size,
                              hipStream_t stream)
{
  const float* q   = (const float*)d_in[0];
  const float* kin = (const float*)d_in[1];
  const float* vin = (const float*)d_in[2];
  const int*   ei  = (const int*)d_in[3];
  const float* Wq  = (const float*)d_in[4];
  const float* Wk  = (const float*)d_in[5];
  const float* Wv  = (const float*)d_in[6];
  const float* Wfc = (const float*)d_in[7];
  const float* g1W = (const float*)d_in[8],  *g1as = (const float*)d_in[9],  *g1ad = (const float*)d_in[10];
  const float* l1W = (const float*)d_in[12], *l1b = (const float*)d_in[13], *g1b = (const float*)d_in[11];
  const float* g2W = (const float*)d_in[14], *g2as = (const float*)d_in[15], *g2ad = (const float*)d_in[16], *g2b = (const float*)d_in[17];
  const float* l2W = (const float*)d_in[18], *l2b = (const float*)d_in[19];
  const float* g3W = (const float*)d_in[20], *g3as = (const float*)d_in[21], *g3ad = (const float*)d_in[22], *g3b = (const float*)d_in[23];
  const float* l3W = (const float*)d_in[24], *l3b = (const float*)d_in[25];
  const float* lng = (const float*)d_in[26], *lnb = (const float*)d_in[27];

  // ---- d_out regions (f32 output) ----
  float* ybuf = (float*)d_out;                          // y: NT*256 f32
  float* attn_out = ybuf + (size_t)NT * 256;            // attn: 32M f32 = 134.2 MB
  bfu* catb = (bfu*)d_out;                              // bf16 [NT][256] in y region

  // GAT scratch in attn region (dead before pv_k writes attn over it)
  char* ap = (char*)attn_out;
  auto take_a = [&](size_t bytes) -> void* {
    void* r = (void*)ap; ap += (bytes + 255) & ~(size_t)255; return r;
  };
  bfu* q_bf = (bfu*)take_a((size_t)NT * 256 * 2);   // q_bf/k_bf/v_bf contiguous (EPI 8)
  bfu* k_bf = (bfu*)take_a((size_t)NT * 256 * 2);
  bfu* v_bf = (bfu*)take_a((size_t)NT * 256 * 2);
  bfu* aggb  = (bfu*)take_a((size_t)NT * 512 * 2);
  float* avsp = (float*)take_a((size_t)NT * 8 * 4);  // alpha-src partials [r][hd][blk][wc]
  float* avdp = (float*)take_a((size_t)NT * 8 * 4);  // alpha-dst partials
  int* deg    = (int*)take_a((size_t)NT * 4);
  int* rowptr = (int*)take_a((size_t)(NT + 1) * 4);
  int* fillc  = (int*)take_a((size_t)NT * 4);
  int* srcs   = (int*)take_a((size_t)ET * 4);

  // ---- d_ws (~117 MB) ----
  char* p = (char*)d_ws;
  auto take = [&](size_t bytes) -> void* {
    void* r = (void*)p; p += (bytes + 255) & ~(size_t)255; return r;
  };
  bfu* hbuf = (bfu*)take((size_t)NT * 512 * 2);
  bfu* x1   = (bfu*)take((size_t)NT * 512 * 2);
  bfu* x2   = (bfu*)take((size_t)NT * 512 * 2);
  bfu* wall = (bfu*)take((size_t)1146880 * 2);               // all converted weights
  bfu* Pbuf = (bfu*)take((size_t)32 * 1048576 * 2);          // bf16 expS [32][1024][1024]
  float* rowsum16 = (float*)take((size_t)32 * 1024 * 16 * 4);// attn row-sum partials [bh][r][16]

  bfu* WqT  = wall;                 // WqT/WkT/WvT contiguous, stride 32768 (EPI 8)
  bfu* WfcT = wall + 98304;
  bfu* g1Wt = wall + 163840;
  bfu* l1Wt = wall + 294912;
  bfu* g2Wt = wall + 425984;
  bfu* l2Wt = wall + 688128;
  bfu* g3Wt = wall + 950272;
  bfu* l3Wt = wall + 1081344;

  // hbuf dead after layer-3 agg -> attention operand aliases
  bfu* qh2  = hbuf;                            // [32][1024][64] (EPI 8 z=0 base)
  bfu* khb2 = hbuf + (size_t)2 * 1024 * 1024;
  bfu* vt   = hbuf + (size_t)4 * 1024 * 1024;  // [32][64][1024]
  float* prelng = (float*)x1;                  // x1 dead after layer-2 gemms

  const int EB = (ET + 255) / 256;
  const long long zs = 0;
  #define NOAL nullptr, nullptr, nullptr, nullptr

  // conversions (fully merged: q/k/v bf16 + all weight transposes + deg zero)
  conv_all<<<dim3(4480, 5), 256, 0, stream>>>(q, kin, vin, q_bf, k_bf, v_bf,
                                              Wq, Wk, Wv, Wfc, g1W, l1W, g2W, l2W, g3W, l3W, wall, deg);

  // CSR build (srcs stored directly)
  csr_count<<<EB, 256, 0, stream>>>(ei, deg);
  csr_scan<<<1, 1024, 0, stream>>>(deg, rowptr, fillc);
  csr_fill<<<EB, 256, 0, stream>>>(ei, fillc, srcs);

  // ---- GAT layer 1 ----
  mgemm<0><<<dim3(4, 128), 256, 0, stream>>>(q_bf, 256, zs, g1Wt, 256, zs, 256, hbuf, nullptr, 512, zs, nullptr, nullptr, nullptr, 0, nullptr, g1as, g1ad, avsp, avdp);
  aggf_k<512, 2><<<NT, 256, 0, stream>>>(rowptr, srcs, avsp, avdp, hbuf, aggb);
  mgemm<1><<<dim3(4, 128), 256, 0, stream>>>(q_bf, 256, zs, l1Wt, 256, zs, 256, x1, nullptr, 512, zs, l1b, g1b, aggb, 512, nullptr, NOAL);

  // ---- GAT layer 2 ----
  mgemm<0><<<dim3(4, 128), 256, 0, stream>>>(x1, 512, zs, g2Wt, 512, zs, 512, hbuf, nullptr, 512, zs, nullptr, nullptr, nullptr, 0, nullptr, g2as, g2ad, avsp, avdp);
  aggf_k<512, 2><<<NT, 256, 0, stream>>>(rowptr, srcs, avsp, avdp, hbuf, aggb);
  mgemm<1><<<dim3(4, 128), 256, 0, stream>>>(x1, 512, zs, l2Wt, 512, zs, 512, x2, nullptr, 512, zs, l2b, g2b, aggb, 512, nullptr, NOAL);
  // x1 now dead.

  // ---- GAT layer 3 -> catb[:,0:128] ----
  mgemm<0><<<dim3(2, 128), 256, 0, stream>>>(x2, 512, zs, g3Wt, 512, zs, 512, hbuf, nullptr, 256, zs, nullptr, nullptr, nullptr, 0, nullptr, g3as, g3ad, avsp, avdp);
  aggf_k<256, 1><<<NT, 256, 0, stream>>>(rowptr, srcs, avsp, avdp, hbuf, aggb);
  mgemm<2><<<dim3(1, 128), 256, 0, stream>>>(x2, 512, zs, l3Wt, 512, zs, 512, catb, nullptr, 256, zs, l3b, g3b, aggb, 256, nullptr, NOAL);
  // hbuf now dead -> qh2/khb2/vt.

  // ---- q/k/v projections, batched over z (head-split layouts) ----
  mgemm<8><<<dim3(1, 128, 3), 256, 0, stream>>>(q_bf, 256, (long long)NT * 256, WqT, 256, 32768LL, 256, qh2, nullptr, 0, zs, nullptr, nullptr, nullptr, 0, nullptr, NOAL);

  // ---- attention: expS bf16 + rowsum partials -> PV (writes normalized f32 attn too) ----
  mgemm<7><<<dim3(8, 8, 32), 256, 0, stream>>>(qh2, 64, 65536LL, khb2, 64, 65536LL, 64, Pbuf, nullptr, 1024, 1048576LL, nullptr, nullptr, nullptr, 0, nullptr, nullptr, nullptr, rowsum16, nullptr);
  pv_k<<<dim3(1, 8, 32), 256, 0, stream>>>(Pbuf, vt, rowsum16, catb, attn_out);

  // ---- final FC + residual + LN ----
  mgemm<3><<<dim3(2, 128), 256, 0, stream>>>(catb, 256, zs, WfcT, 256, zs, 256, nullptr, prelng, 256, zs, nullptr, nullptr, nullptr, 0, q, NOAL);
  ln_k<<<NT, 256, 0, stream>>>(prelng, lng, lnb, ybuf);
}